// Round 8
// baseline (53.229 us; speedup 1.0000x reference)
//
#include <hip/hip_runtime.h>
#include <hip/hip_bf16.h>

// ---- problem constants ----
#define BATCH  65536
#define KREAL  784          // 28*28 = GEMM-K (conv folded into Weff)
#define BK     64           // B sub-chunk (compute granularity)
#define NCHUNK 13           // 13 x 64 = 832 >= 784
#define HID    128
#define NOUT   10
#define BM     128          // rows per block
#define NTHR   512          // 8 waves

using f32x4  = __attribute__((ext_vector_type(4))) float;
using short8 = __attribute__((ext_vector_type(8))) short;   // 8 bf16
using short4v= __attribute__((ext_vector_type(4))) short;   // 4 bf16 (8 B)
using f4     = __attribute__((ext_vector_type(4))) float;

__device__ inline short f2b(float f) {
    union { __hip_bfloat16 h; short s; } u;
    u.h = __float2bfloat16(f);               // hardware RNE cvt
    return u.s;
}

// global -> LDS direct copy, 16 B per lane. gp: PER-LANE global addr,
// lp: wave-uniform LDS base (HW writes base + lane*16).
#define GLDS16(gp, lp) \
    __builtin_amdgcn_global_load_lds((const __attribute__((address_space(1))) void*)(gp), \
                                     (__attribute__((address_space(3))) void*)(lp), 16, 0, 0)

// ---------------------------------------------------------------------------
// Prep (unchanged, proven):
//  weff_sw[ic][r][cc] = Weff[r][ic*64 + ((cc>>3)^(r&7))*8 + (cc&7)]  (bf16)
//  w2f fragment-ordered: ((kk*4+hi)*16+lo)*8+e <-> w2[lo][kk*32+hi*8+e]
// ---------------------------------------------------------------------------
#define NWB (NCHUNK*HID*BK)   // 106496
#define NW2 (4*4*16*8)        // 2048

__global__ void prep_kernel(const float* __restrict__ conv_w,
                            const float* __restrict__ w1,
                            const float* __restrict__ w2,
                            unsigned short* __restrict__ weff_sw,
                            unsigned short* __restrict__ w2f)
{
    int idx = blockIdx.x * 256 + threadIdx.x;
    if (idx < NWB) {
        int ic  = idx >> 13;
        int rem = idx & 8191;
        int r   = rem >> 6;
        int cc  = rem & 63;
        int g   = (cc >> 3) ^ (r & 7);
        int k   = ic * BK + g * 8 + (cc & 7);
        float acc = 0.f;
        if (k < KREAL) {
            int rr = k / 28, c = k - rr * 28;
            #pragma unroll
            for (int di = 0; di < 3; ++di) {
                int i = rr - di;
                if (i >= 0 && i < 26) {
                    #pragma unroll
                    for (int dj = 0; dj < 3; ++dj) {
                        int j = c - dj;
                        if (j >= 0 && j < 26)
                            acc = fmaf(w1[r * 676 + i * 26 + j], conv_w[di * 3 + dj], acc);
                    }
                }
            }
        }
        weff_sw[idx] = (unsigned short)f2b(acc);
    } else {
        int k2 = idx - NWB;
        if (k2 < NW2) {
            int e  = k2 & 7;
            int lo = (k2 >> 3) & 15;
            int hi = (k2 >> 7) & 3;
            int kk = k2 >> 9;
            float v = (lo < NOUT) ? w2[lo * HID + kk * 32 + hi * 8 + e] : 0.f;
            w2f[k2] = (unsigned short)f2b(v);
        }
    }
}

// ---------------------------------------------------------------------------
// Fused: relu(x @ Weff^T + b1) @ w2^T + b2
// KEY CHANGE vs r7: A staged in 256-col SUPER-chunks. Each wave-instruction
// reads ONE full row x 1 KB contiguous (fill-kernel burst shape), 16 instrs
// per super-chunk per wave. A tile [128][256] bf16, wave-private, single
// buffer, XOR-16B swizzled (g16 ^ (r&15)). B keeps r7's proven 64-col
// double-buffered global_load_lds path with one bare barrier per subchunk
// and exact static vmcnt counts.
// LDS 96 KB (extern) -> 1 block/CU, 8 waves.
// ---------------------------------------------------------------------------
__global__ __launch_bounds__(NTHR, 2)
void fused_mlp_kernel(const float* __restrict__ x,
                      const float* __restrict__ b1,
                      const float* __restrict__ b2,
                      const unsigned short* __restrict__ weff_sw,
                      const unsigned short* __restrict__ w2f,
                      float* __restrict__ out)
{
    extern __shared__ __align__(16) unsigned char smem[];    // 96 KB dynamic
    unsigned short* ldsA  = (unsigned short*)smem;           // [128][256] bf16 swz, 64 KB
    unsigned short* ldsB0 = (unsigned short*)(smem + 65536); // [128][64] bf16 swz, 16 KB
    unsigned short* ldsB1 = (unsigned short*)(smem + 81920);
    unsigned short* ldsH  = (unsigned short*)smem;           // [128][128] alias (post-loop)
    float*          outS  = (float*)(smem + 65536);          // alias B0 (post-loop)

    const int tid  = threadIdx.x;
    const int wv   = tid >> 6;
    const int lane = tid & 63;
    const int lo   = lane & 15;
    const int hi   = lane >> 4;
    const int row0 = blockIdx.x * BM;
    const int wr0  = wv * 16;

    f32x4 acc[8];
    #pragma unroll
    for (int t = 0; t < 8; ++t) acc[t] = (f32x4){0.f, 0.f, 0.f, 0.f};

    // ---- A staging: 16 instrs/wave, each = 1 row x 1 KB contiguous ----
    f4 av[16];
    const char* abase = (const char*)x + (long)(row0 + wr0) * (KREAL * 4);
    auto issueA = [&](int sc) {
        #pragma unroll
        for (int j = 0; j < 16; ++j) {
            int ce = sc * 256 + lane * 4;                    // first fp32 col
            int cb = (ce + 4 <= KREAL) ? ce : 0;             // clamp (sc=3 only; B zero there)
            av[j] = *(const f4*)(abase + (long)j * (KREAL * 4) + (long)cb * 4);
        }
    };
    // cvt + swizzled b64 writes into the wave's OWN 16 rows (wave-private).
    auto writeA = [&]() {
        #pragma unroll
        for (int j = 0; j < 16; ++j) {
            int r = wr0 + j;
            short4v c;
            c[0] = f2b(av[j][0]); c[1] = f2b(av[j][1]);
            c[2] = f2b(av[j][2]); c[3] = f2b(av[j][3]);
            int byteoff = r * 512 + ((((lane >> 1) ^ (r & 15)) << 4)) + ((lane & 1) << 3);
            *(short4v*)((char*)ldsA + byteoff) = c;
        }
    };
    auto stageB = [&](int ic, unsigned short* dst) {
        const char* src = (const char*)(weff_sw + (long)ic * (HID * BK));
        GLDS16(src + wv * 2048 + lane * 16,        (char*)dst + wv * 2048);
        GLDS16(src + wv * 2048 + 1024 + lane * 16, (char*)dst + wv * 2048 + 1024);
    };

    // ---- prologue: A(0) + B(0) ----
    stageB(0, ldsB0);                    // queue [B2]
    issueA(0);                           // queue [B2, A16]
    asm volatile("s_waitcnt vmcnt(0)" ::: "memory");
    __builtin_amdgcn_sched_barrier(0);
    writeA();                            // A(0) -> LDS (own rows)
    __builtin_amdgcn_s_barrier();        // B(0) visible everywhere
    __builtin_amdgcn_sched_barrier(0);

    #pragma unroll
    for (int c = 0; c < NCHUNK; ++c) {
        const int sc = c >> 2;           // A super-chunk
        const int u  = c & 3;            // subchunk within super-chunk
        const unsigned short* Bc = (c & 1) ? ldsB1 : ldsB0;

        if (c + 1 < NCHUNK)
            stageB(c + 1, (c & 1) ? ldsB0 : ldsB1);          // +B2
        if (u == 2 && sc < 3)
            issueA(sc + 1);                                  // +A16 (after B2)

        // ---- compute subchunk c: 2 k-substeps x 8 n-tiles ----
        const int r = wr0 + lo;
        #pragma unroll
        for (int kk = 0; kk < 2; ++kk) {
            const int GA = u * 8 + kk * 4 + hi;              // A granule16 [0,32)
            short8 af = *(const short8*)((const char*)ldsA + r * 512 + ((GA ^ (r & 15)) << 4));
            const int GB = kk * 4 + hi;                      // B granule16 [0,8)
            #pragma unroll
            for (int t = 0; t < 8; ++t) {
                const int ob = t * 16 + lo;
                short8 bfrag = *(const short8*)&Bc[ob * BK + ((GB ^ (ob & 7)) << 3)];
                acc[t] = __builtin_amdgcn_mfma_f32_16x16x32_bf16(af, bfrag, acc[t], 0, 0, 0);
            }
        }

        if (c + 1 < NCHUNK) {
            __builtin_amdgcn_sched_barrier(0);
            if (u == 3) {
                // queue: [A16 (from u==2), B2 (this subchunk)]
                asm volatile("s_waitcnt vmcnt(2)" ::: "memory");   // A16 done
                __builtin_amdgcn_sched_barrier(0);
                writeA();                                          // A(sc+1), own rows
                __builtin_amdgcn_sched_barrier(0);
                asm volatile("s_waitcnt vmcnt(0)" ::: "memory");   // B(c+1) done
            } else if (u == 2) {
                // queue: [B2, A16] -> wait only B
                asm volatile("s_waitcnt vmcnt(16)" ::: "memory");
            } else {
                // queue: [B2]
                asm volatile("s_waitcnt vmcnt(0)" ::: "memory");
            }
            __builtin_amdgcn_sched_barrier(0);
            __builtin_amdgcn_s_barrier();   // B(c+1) (and A(sc+1) at u==3) visible
            __builtin_amdgcn_sched_barrier(0);
        }
    }

    __builtin_amdgcn_sched_barrier(0);
    __builtin_amdgcn_s_barrier();        // all compute done before ldsH/outS alias writes
    __builtin_amdgcn_sched_barrier(0);

    // ---- FC1 epilogue: +b1, ReLU, h -> swizzled per-wave ldsH slice ----
    // C/D layout: col = lane&15, row = (lane>>4)*4 + reg
    #pragma unroll
    for (int t = 0; t < 8; ++t) {
        float bias = b1[t * 16 + lo];
        #pragma unroll
        for (int j = 0; j < 4; ++j) {
            float hv = acc[t][j] + bias;
            hv = hv > 0.f ? hv : 0.f;
            int rloc = wr0 + hi * 4 + j;
            int col  = t * 16 + lo;
            int g    = col >> 3, e = col & 7;
            ldsH[rloc * HID + ((g ^ (rloc & 7)) << 3) + e] = (unsigned short)f2b(hv);
        }
    }
    // wave reads only its own writes below -> no barrier

    // ---- FC2: h[16x128] @ w2^T[128x16] per wave, 4 MFMAs ----
    f32x4 acc2 = (f32x4){0.f, 0.f, 0.f, 0.f};
    #pragma unroll
    for (int kk = 0; kk < 4; ++kk) {
        int r = wr0 + lo;
        int g = kk * 4 + hi;
        short8 ha = *(const short8*)&ldsH[r * HID + ((g ^ (r & 7)) << 3)];
        short8 wb = *(const short8*)(w2f + (((kk * 4 + hi) * 16 + lo) << 3));
        acc2 = __builtin_amdgcn_mfma_f32_16x16x32_bf16(ha, wb, acc2, 0, 0, 0);
    }
    // stage [16][10] f32 in the wave's outS slice, then one contiguous 640-B store
    float* os = outS + wv * 160;
    if (lo < NOUT) {
        float bb = b2[lo];
        #pragma unroll
        for (int j = 0; j < 4; ++j)
            os[(hi * 4 + j) * NOUT + lo] = acc2[j] + bb;
    }
    if (lane < 40) {
        f4 v = *(const f4*)&os[lane * 4];
        *(f4*)(out + (long)(row0 + wr0) * NOUT + lane * 4) = v;
    }
}

// ---------------------------------------------------------------------------
extern "C" void kernel_launch(void* const* d_in, const int* in_sizes, int n_in,
                              void* d_out, int out_size, void* d_ws, size_t ws_size,
                              hipStream_t stream)
{
    const float* x      = (const float*)d_in[0];
    const float* conv_w = (const float*)d_in[1];
    const float* w1     = (const float*)d_in[2];
    const float* b1     = (const float*)d_in[3];
    const float* w2     = (const float*)d_in[4];
    const float* b2     = (const float*)d_in[5];
    float* out = (float*)d_out;

    unsigned short* weff_sw = (unsigned short*)d_ws;    // 106496 bf16
    unsigned short* w2f     = weff_sw + NWB;            // 2048 bf16

    const int prep_total = NWB + NW2;                   // 108544
    prep_kernel<<<(prep_total + 255) / 256, 256, 0, stream>>>(conv_w, w1, w2, weff_sw, w2f);
    fused_mlp_kernel<<<BATCH / BM, NTHR, 98304, stream>>>(x, b1, b2, weff_sw, w2f, out);
}

// Round 9
// 49.442 us; speedup vs baseline: 1.0766x; 1.0766x over previous
//
#include <hip/hip_runtime.h>
#include <hip/hip_bf16.h>

// ---- problem constants ----
#define BATCH  65536
#define KREAL  784          // 28*28 = GEMM-K (conv folded into Weff)
#define BKW    128          // K-chunk cols
#define NCH    7            // 6 full chunks + 1 tail (1 substep)
#define HID    128
#define NOUT   10
#define BM     256          // rows per block
#define NTHR   512          // 8 waves x 32 rows each; grid = 256 = 1 block/CU

using f32x4  = __attribute__((ext_vector_type(4))) float;
using short8 = __attribute__((ext_vector_type(8))) short;   // 8 bf16
using short4v= __attribute__((ext_vector_type(4))) short;   // 4 bf16 (8 B)
using f4     = __attribute__((ext_vector_type(4))) float;

__device__ inline short f2b(float f) {
    union { __hip_bfloat16 h; short s; } u;
    u.h = __float2bfloat16(f);               // hardware RNE cvt
    return u.s;
}

// global -> LDS direct copy, 16 B per lane. gp: PER-LANE global addr,
// lp: wave-uniform LDS base (HW writes base + lane*16).
#define GLDS16(gp, lp) \
    __builtin_amdgcn_global_load_lds((const __attribute__((address_space(1))) void*)(gp), \
                                     (__attribute__((address_space(3))) void*)(lp), 16, 0, 0)

// ---------------------------------------------------------------------------
// Prep:
//  weff_sw: conv folded into w1, bf16, 128-col chunk-major, PRE-SWIZZLED:
//    weff_sw[ic][r][cc] = Weff[r][ic*128 + ((cc>>3)^(r&15))*8 + (cc&7)]
//  (flat granule position p holds logical granule p^(r&15); zero for k>=784)
//  w2f fragment-ordered: ((kk*4+hi)*16+lo)*8+e <-> w2[lo][kk*32+hi*8+e]
// ---------------------------------------------------------------------------
#define NWB (NCH*HID*BKW)     // 114688
#define NW2 (4*4*16*8)        // 2048

__global__ void prep_kernel(const float* __restrict__ conv_w,
                            const float* __restrict__ w1,
                            const float* __restrict__ w2,
                            unsigned short* __restrict__ weff_sw,
                            unsigned short* __restrict__ w2f)
{
    int idx = blockIdx.x * 256 + threadIdx.x;
    if (idx < NWB) {
        int ic  = idx >> 14;                 // /(128*128)
        int rem = idx & 16383;
        int r   = rem >> 7;
        int cc  = rem & 127;
        int g   = (cc >> 3) ^ (r & 15);
        int k   = ic * BKW + g * 8 + (cc & 7);
        float acc = 0.f;
        if (k < KREAL) {
            int rr = k / 28, c = k - rr * 28;
            #pragma unroll
            for (int di = 0; di < 3; ++di) {
                int i = rr - di;
                if (i >= 0 && i < 26) {
                    #pragma unroll
                    for (int dj = 0; dj < 3; ++dj) {
                        int j = c - dj;
                        if (j >= 0 && j < 26)
                            acc = fmaf(w1[r * 676 + i * 26 + j], conv_w[di * 3 + dj], acc);
                    }
                }
            }
        }
        weff_sw[idx] = (unsigned short)f2b(acc);
    } else {
        int k2 = idx - NWB;
        if (k2 < NW2) {
            int e  = k2 & 7;
            int lo = (k2 >> 3) & 15;
            int hi = (k2 >> 7) & 3;
            int kk = k2 >> 9;
            float v = (lo < NOUT) ? w2[lo * HID + kk * 32 + hi * 8 + e] : 0.f;
            w2f[k2] = (unsigned short)f2b(v);
        }
    }
}

// ---------------------------------------------------------------------------
// Fused: relu(x @ Weff^T + b1) @ w2^T + b2
// BK=128: 7 chunks. A staged as 512-B contiguous runs (2 rows/instr),
// wave-private single-buffer LDS [256][128]bf16 (no A barrier ever).
// B: pre-swizzled weff chunk via global_load_lds, double-buffered.
// One bare s_barrier + one vmcnt(0) per chunk, a full chunk after issue.
// 256 blocks x 512 thr = 1 block/CU, fully resident. LDS 128 KB.
// ---------------------------------------------------------------------------
__global__ __launch_bounds__(NTHR, 2)
void fused_mlp_kernel(const float* __restrict__ x,
                      const float* __restrict__ b1,
                      const float* __restrict__ b2,
                      const unsigned short* __restrict__ weff_sw,
                      const unsigned short* __restrict__ w2f,
                      float* __restrict__ out)
{
    extern __shared__ __align__(16) unsigned char smem[];    // 128 KB dynamic
    unsigned short* ldsA  = (unsigned short*)smem;           // [256][128]bf16 swz, 64 KB
    unsigned short* ldsB0 = (unsigned short*)(smem + 65536); // [128][128]bf16 swz, 32 KB
    unsigned short* ldsB1 = (unsigned short*)(smem + 98304);
    unsigned short* ldsH  = (unsigned short*)smem;           // [256][128] alias (post-loop)
    float*          outS  = (float*)(smem + 65536);          // alias B0 (post-loop)

    const int tid  = threadIdx.x;
    const int wv   = tid >> 6;
    const int lane = tid & 63;
    const int lo   = lane & 15;
    const int hi   = lane >> 4;
    const int row0 = blockIdx.x * BM;
    const int wr0  = wv * 32;                // wave owns rows [wr0, wr0+32)

    f32x4 acc[2][8];
    #pragma unroll
    for (int m = 0; m < 2; ++m)
        #pragma unroll
        for (int t = 0; t < 8; ++t) acc[m][t] = (f32x4){0.f, 0.f, 0.f, 0.f};

    // ---- A staging: 16 instrs/wave/chunk, each = 2 rows x 512 B contiguous
    f4 av[16];
    const char* abase = (const char*)x + (long)(row0 + wr0) * (KREAL * 4);
    auto issueA = [&](int c) {
        #pragma unroll
        for (int j = 0; j < 16; ++j) {
            int rr = j * 2 + (lane >> 5);                    // local row 0..31
            int ce = c * BKW + (lane & 31) * 4;              // first fp32 col
            int cb = (ce + 4 <= KREAL) ? ce : 0;             // clamp; junk x B=0
            av[j] = *(const f4*)(abase + (long)rr * (KREAL * 4) + (long)cb * 4);
        }
    };
    // cvt + swizzled b64 writes into the wave's OWN rows (wave-private).
    auto writeA = [&]() {
        #pragma unroll
        for (int j = 0; j < 16; ++j) {
            int r  = wr0 + j * 2 + (lane >> 5);
            int sg = (lane & 31) >> 1;                       // col granule16 0..15
            short4v c;
            c[0] = f2b(av[j][0]); c[1] = f2b(av[j][1]);
            c[2] = f2b(av[j][2]); c[3] = f2b(av[j][3]);
            int byteoff = r * 256 + ((sg ^ (r & 15)) << 4) + ((lane & 1) << 3);
            *(short4v*)((char*)ldsA + byteoff) = c;
        }
    };
    auto stageB = [&](int c, unsigned short* dst) {
        const char* src = (const char*)(weff_sw + (long)c * (HID * BKW));
        #pragma unroll
        for (int q = 0; q < 4; ++q)
            GLDS16(src + q * 8192 + wv * 1024 + lane * 16,
                   (char*)dst + q * 8192 + wv * 1024);
    };

    // ---- prologue: chunk 0 ----
    issueA(0);
    stageB(0, ldsB0);
    writeA();                                 // compiler inserts exact vmcnt for av
    asm volatile("s_waitcnt vmcnt(0)" ::: "memory");
    __builtin_amdgcn_sched_barrier(0);
    __builtin_amdgcn_s_barrier();             // B(0) + everyone's A(0) visible
    __builtin_amdgcn_sched_barrier(0);

    #pragma unroll
    for (int c = 0; c < NCH; ++c) {
        const unsigned short* Bc = (c & 1) ? ldsB1 : ldsB0;
        if (c + 1 < NCH) {
            issueA(c + 1);                    // 16 reg loads (full chunk to land)
            stageB(c + 1, (c & 1) ? ldsB0 : ldsB1);   // 4 glds (WAR-safe: entry barrier)
        }
        // ---- compute chunk c ----
        const int NS = (c == NCH - 1) ? 1 : 4;       // tail: K=768..799 only
        #pragma unroll
        for (int ks = 0; ks < NS; ++ks) {
            const int G  = ks * 4 + hi;              // granule16 0..15
            const int r0 = wr0 + lo, r1 = wr0 + 16 + lo;
            short8 af0 = *(const short8*)((const char*)ldsA + r0 * 256 + ((G ^ (r0 & 15)) << 4));
            short8 af1 = *(const short8*)((const char*)ldsA + r1 * 256 + ((G ^ (r1 & 15)) << 4));
            #pragma unroll
            for (int t = 0; t < 8; ++t) {
                const int ob = t * 16 + lo;
                short8 bf = *(const short8*)((const char*)Bc + ob * 256 + ((G ^ (ob & 15)) << 4));
                acc[0][t] = __builtin_amdgcn_mfma_f32_16x16x32_bf16(af0, bf, acc[0][t], 0, 0, 0);
                acc[1][t] = __builtin_amdgcn_mfma_f32_16x16x32_bf16(af1, bf, acc[1][t], 0, 0, 0);
            }
        }
        if (c + 1 < NCH) {
            __builtin_amdgcn_sched_barrier(0);
            writeA();                          // own rows; after own reads (DS in-order)
            __builtin_amdgcn_sched_barrier(0);
            asm volatile("s_waitcnt vmcnt(0)" ::: "memory");   // B(c+1) landed
            __builtin_amdgcn_sched_barrier(0);
            __builtin_amdgcn_s_barrier();      // B(c+1) visible everywhere
            __builtin_amdgcn_sched_barrier(0);
        }
    }

    __builtin_amdgcn_sched_barrier(0);
    __builtin_amdgcn_s_barrier();              // all compute done before alias writes
    __builtin_amdgcn_sched_barrier(0);

    // ---- FC1 epilogue: +b1, ReLU, h -> swizzled per-wave ldsH slice ----
    // C/D layout: col = lane&15, row = (lane>>4)*4 + reg
    #pragma unroll
    for (int m = 0; m < 2; ++m) {
        #pragma unroll
        for (int t = 0; t < 8; ++t) {
            float bias = b1[t * 16 + lo];
            #pragma unroll
            for (int j = 0; j < 4; ++j) {
                float hv = acc[m][t][j] + bias;
                hv = hv > 0.f ? hv : 0.f;
                int rloc = wr0 + m * 16 + hi * 4 + j;
                int col  = t * 16 + lo;
                int g    = col >> 3, e = col & 7;
                ldsH[rloc * HID + ((g ^ (rloc & 7)) << 3) + e] = (unsigned short)f2b(hv);
            }
        }
    }
    // wave reads only its own writes below -> no barrier

    // ---- FC2: per m-tile, h[16x128] @ w2^T[128x16], 4 MFMAs ----
    float* os = outS + wv * 320;               // [32][10] f32 per wave
    #pragma unroll
    for (int m = 0; m < 2; ++m) {
        f32x4 acc2 = (f32x4){0.f, 0.f, 0.f, 0.f};
        #pragma unroll
        for (int kk = 0; kk < 4; ++kk) {
            int r = wr0 + m * 16 + lo;
            int g = kk * 4 + hi;
            short8 ha = *(const short8*)&ldsH[r * HID + ((g ^ (r & 7)) << 3)];
            short8 wb = *(const short8*)(w2f + (((kk * 4 + hi) * 16 + lo) << 3));
            acc2 = __builtin_amdgcn_mfma_f32_16x16x32_bf16(ha, wb, acc2, 0, 0, 0);
        }
        if (lo < NOUT) {
            float bb = b2[lo];
            #pragma unroll
            for (int j = 0; j < 4; ++j)
                os[(m * 16 + hi * 4 + j) * NOUT + lo] = acc2[j] + bb;
        }
    }
    // contiguous 640-B stores per 16-row group
    #pragma unroll
    for (int s = 0; s < 2; ++s) {
        if (lane < 40) {
            f4 v = *(const f4*)&os[s * 160 + lane * 4];
            *(f4*)(out + (long)(row0 + wr0 + s * 16) * NOUT + lane * 4) = v;
        }
    }
}

// ---------------------------------------------------------------------------
extern "C" void kernel_launch(void* const* d_in, const int* in_sizes, int n_in,
                              void* d_out, int out_size, void* d_ws, size_t ws_size,
                              hipStream_t stream)
{
    const float* x      = (const float*)d_in[0];
    const float* conv_w = (const float*)d_in[1];
    const float* w1     = (const float*)d_in[2];
    const float* b1     = (const float*)d_in[3];
    const float* w2     = (const float*)d_in[4];
    const float* b2     = (const float*)d_in[5];
    float* out = (float*)d_out;

    unsigned short* weff_sw = (unsigned short*)d_ws;    // 114688 bf16
    unsigned short* w2f     = weff_sw + NWB;            // 2048 bf16

    const int prep_total = NWB + NW2;                   // 116736
    prep_kernel<<<(prep_total + 255) / 256, 256, 0, stream>>>(conv_w, w1, w2, weff_sw, w2f);
    fused_mlp_kernel<<<BATCH / BM, NTHR, 131072, stream>>>(x, b1, b2, weff_sw, w2f, out);
}

// Round 10
// 43.302 us; speedup vs baseline: 1.2293x; 1.1418x over previous
//
#include <hip/hip_runtime.h>
#include <hip/hip_bf16.h>

// ---- problem constants ----
#define BATCH  65536
#define KREAL  784          // 28*28 = GEMM-K (conv folded into Weff)
#define BK     64
#define NCHUNK 13
#define HID    128
#define NOUT   10
#define BM     64           // rows per block
#define NTHR   256          // 4 waves; grid = 1024 = exactly 4 blocks/CU

using f32x4  = __attribute__((ext_vector_type(4))) float;
using short8 = __attribute__((ext_vector_type(8))) short;   // 8 bf16
using short4v= __attribute__((ext_vector_type(4))) short;   // 4 bf16 (8 B)
using f4     = __attribute__((ext_vector_type(4))) float;

__device__ inline short f2b(float f) {
    union { __hip_bfloat16 h; short s; } u;
    u.h = __float2bfloat16(f);               // hardware RNE cvt
    return u.s;
}

// global -> LDS direct copy, 16 B per lane. gp: PER-LANE global addr,
// lp: wave-uniform LDS base (HW writes base + lane*16).
#define GLDS16(gp, lp) \
    __builtin_amdgcn_global_load_lds((const __attribute__((address_space(1))) void*)(gp), \
                                     (__attribute__((address_space(3))) void*)(lp), 16, 0, 0)

// ---------------------------------------------------------------------------
// Prep (unchanged, proven):
//  weff_sw[ic][r][cc] = Weff[r][ic*64 + ((cc>>3)^(r&7))*8 + (cc&7)]  (bf16,
//  zero for k>=784) — a linear copy of chunk ic IS the swizzled LDS B-tile.
//  w2f fragment-ordered: ((kk*4+hi)*16+lo)*8+e <-> w2[lo][kk*32+hi*8+e]
// ---------------------------------------------------------------------------
#define NWB (NCHUNK*HID*BK)   // 106496
#define NW2 (4*4*16*8)        // 2048

__global__ void prep_kernel(const float* __restrict__ conv_w,
                            const float* __restrict__ w1,
                            const float* __restrict__ w2,
                            unsigned short* __restrict__ weff_sw,
                            unsigned short* __restrict__ w2f)
{
    int idx = blockIdx.x * 256 + threadIdx.x;
    if (idx < NWB) {
        int ic  = idx >> 13;
        int rem = idx & 8191;
        int r   = rem >> 6;
        int cc  = rem & 63;
        int g   = (cc >> 3) ^ (r & 7);
        int k   = ic * BK + g * 8 + (cc & 7);
        float acc = 0.f;
        if (k < KREAL) {
            int rr = k / 28, c = k - rr * 28;
            #pragma unroll
            for (int di = 0; di < 3; ++di) {
                int i = rr - di;
                if (i >= 0 && i < 26) {
                    #pragma unroll
                    for (int dj = 0; dj < 3; ++dj) {
                        int j = c - dj;
                        if (j >= 0 && j < 26)
                            acc = fmaf(w1[r * 676 + i * 26 + j], conv_w[di * 3 + dj], acc);
                    }
                }
            }
        }
        weff_sw[idx] = (unsigned short)f2b(acc);
    } else {
        int k2 = idx - NWB;
        if (k2 < NW2) {
            int e  = k2 & 7;
            int lo = (k2 >> 3) & 15;
            int hi = (k2 >> 7) & 3;
            int kk = k2 >> 9;
            float v = (lo < NOUT) ? w2[lo * HID + kk * 32 + hi * 8 + e] : 0.f;
            w2f[k2] = (unsigned short)f2b(v);
        }
    }
}

// ---------------------------------------------------------------------------
// Fused: relu(x @ Weff^T + b1) @ w2^T + b2
// BM=64, 256 thr (4 waves), 1024 blocks = 4 blocks/CU (16 waves/CU, LDS
// 40 KB exact fit). Chunk-STAGGERED K-sweep: block b starts at chunk b%13
// (de-phases weff L2 + x column herd). A: reg-staged, single LDS buffer,
// wave-private rows (writeA after own reads; per-wave DS in-order). B:
// pre-swizzled weff via global_load_lds, double-buffered. One bare
// s_barrier + one vmcnt(0) per chunk, after the compute overlap window.
// ---------------------------------------------------------------------------
__global__ __launch_bounds__(NTHR, 4)
void fused_mlp_kernel(const float* __restrict__ x,
                      const float* __restrict__ b1,
                      const float* __restrict__ b2,
                      const unsigned short* __restrict__ weff_sw,
                      const unsigned short* __restrict__ w2f,
                      float* __restrict__ out)
{
    __shared__ __align__(16) unsigned char smem[40960];      // 40 KB
    unsigned short* ldsA  = (unsigned short*)smem;           // [64][64] bf16 swz, 8 KB (single)
    unsigned short* ldsB0 = (unsigned short*)(smem + 8192);  // [128][64] bf16 swz, 16 KB
    unsigned short* ldsB1 = (unsigned short*)(smem + 24576);
    unsigned short* ldsH  = (unsigned short*)smem;           // [64][128] alias (post-loop)
    float*          outS  = (float*)(smem + 16384);          // [64][10] f32 alias (post-loop)

    const int tid  = threadIdx.x;
    const int wv   = tid >> 6;
    const int lane = tid & 63;
    const int lo   = lane & 15;
    const int hi   = lane >> 4;
    const int row0 = blockIdx.x * BM;
    const int wr0  = wv * 16;
    const int c0   = blockIdx.x % NCHUNK;    // stagger start chunk

    f32x4 acc[8];
    #pragma unroll
    for (int t = 0; t < 8; ++t) acc[t] = (f32x4){0.f, 0.f, 0.f, 0.f};

    // A staging: instr j covers rows wr0+j*4+hi, 16 lanes x 16 B = 256 B/row run.
    const char* abase = (const char*)(x + (long)(row0 + wr0 + hi) * KREAL);
    f4 av[4];
    auto issueA = [&](int ic) {
        #pragma unroll
        for (int j = 0; j < 4; ++j) {
            int ce = ic * BK + lo * 4;
            int cb = (ce + 4 <= KREAL) ? ce : 0;   // clamp; weff zero for k>=784
            av[j] = *(const f4*)(abase + (long)j * 4 * KREAL * 4 + (long)cb * 4);
        }
    };
    // cvt + swizzled b64 writes into the wave's OWN rows (wave-private).
    auto writeA = [&]() {
        #pragma unroll
        for (int j = 0; j < 4; ++j) {
            int r = wr0 + j * 4 + hi;
            short4v c;
            c[0] = f2b(av[j][0]); c[1] = f2b(av[j][1]);
            c[2] = f2b(av[j][2]); c[3] = f2b(av[j][3]);
            int byteoff = r * 128 + ((((lo >> 1) ^ (r & 7)) << 4)) + ((lo & 1) << 3);
            *(short4v*)((char*)ldsA + byteoff) = c;
        }
    };
    auto stageB = [&](int ic, unsigned short* dst) {
        const char* src = (const char*)(weff_sw + (long)ic * (HID * BK));
        #pragma unroll
        for (int j = 0; j < 4; ++j)
            GLDS16(src + wv * 4096 + j * 1024 + lane * 16,
                   (char*)dst + wv * 4096 + j * 1024);
    };

    // ---- prologue: chunk c0 ----
    issueA(c0);                              // 4 reg loads (oldest)
    stageB(c0, ldsB0);                       // 4 glds
    writeA();                                // compiler waits only the av loads
    asm volatile("s_waitcnt vmcnt(0)" ::: "memory");
    __builtin_amdgcn_sched_barrier(0);
    __builtin_amdgcn_s_barrier();            // A+B of first chunk visible
    __builtin_amdgcn_sched_barrier(0);

    #pragma unroll
    for (int s = 0; s < NCHUNK; ++s) {
        int ic  = c0 + s;     if (ic >= NCHUNK)  ic -= NCHUNK;
        int icn = ic + 1;     if (icn >= NCHUNK) icn -= NCHUNK;
        const unsigned short* Bc = (s & 1) ? ldsB1 : ldsB0;
        if (s + 1 < NCHUNK) {
            issueA(icn);                     // av loads first (oldest)
            stageB(icn, (s & 1) ? ldsB0 : ldsB1);   // WAR-safe: entry barrier
        }
        // ---- compute chunk ic ----
        const int r = wr0 + lo;
        #pragma unroll
        for (int kk = 0; kk < 2; ++kk) {
            const int G = kk * 4 + hi;
            short8 af = *(const short8*)((const char*)ldsA + r * 128 + ((G ^ (r & 7)) << 4));
            #pragma unroll
            for (int t = 0; t < 8; ++t) {
                const int ob = t * 16 + lo;
                short8 bfrag = *(const short8*)&Bc[ob * BK + ((G ^ (ob & 7)) << 3)];
                acc[t] = __builtin_amdgcn_mfma_f32_16x16x32_bf16(af, bfrag, acc[t], 0, 0, 0);
            }
        }
        if (s + 1 < NCHUNK) {
            __builtin_amdgcn_sched_barrier(0);
            writeA();                        // own rows, after own reads (DS in-order);
                                             // compiler-waits av only, B still in flight
            __builtin_amdgcn_sched_barrier(0);
            asm volatile("s_waitcnt vmcnt(0)" ::: "memory");   // B(icn) landed
            __builtin_amdgcn_sched_barrier(0);
            __builtin_amdgcn_s_barrier();    // next chunk visible block-wide
            __builtin_amdgcn_sched_barrier(0);
        }
    }

    __builtin_amdgcn_sched_barrier(0);
    __builtin_amdgcn_s_barrier();            // all compute done before alias writes
    __builtin_amdgcn_sched_barrier(0);

    // ---- FC1 epilogue: +b1, ReLU, h -> swizzled per-wave ldsH slice ----
    // C/D layout: col = lane&15, row = (lane>>4)*4 + reg
    #pragma unroll
    for (int t = 0; t < 8; ++t) {
        float bias = b1[t * 16 + lo];
        #pragma unroll
        for (int j = 0; j < 4; ++j) {
            float hv = acc[t][j] + bias;
            hv = hv > 0.f ? hv : 0.f;
            int rloc = wr0 + hi * 4 + j;
            int col  = t * 16 + lo;
            int g    = col >> 3, e = col & 7;
            ldsH[rloc * HID + ((g ^ (rloc & 7)) << 3) + e] = (unsigned short)f2b(hv);
        }
    }
    // wave reads only its own writes below -> no barrier

    // ---- FC2: h[16x128] @ w2^T[128x16] per wave, 4 MFMAs ----
    f32x4 acc2 = (f32x4){0.f, 0.f, 0.f, 0.f};
    #pragma unroll
    for (int kk = 0; kk < 4; ++kk) {
        int r = wr0 + lo;
        int g = kk * 4 + hi;
        short8 ha = *(const short8*)&ldsH[r * HID + ((g ^ (r & 7)) << 3)];
        short8 wb = *(const short8*)(w2f + (((kk * 4 + hi) * 16 + lo) << 3));
        acc2 = __builtin_amdgcn_mfma_f32_16x16x32_bf16(ha, wb, acc2, 0, 0, 0);
    }
    // stage [16][10] f32 in the wave's outS slice, then one contiguous 640-B store
    float* os = outS + wv * 160;
    if (lo < NOUT) {
        float bb = b2[lo];
        #pragma unroll
        for (int j = 0; j < 4; ++j)
            os[(hi * 4 + j) * NOUT + lo] = acc2[j] + bb;
    }
    if (lane < 40) {
        f4 v = *(const f4*)&os[lane * 4];
        *(f4*)(out + (long)(row0 + wr0) * NOUT + lane * 4) = v;
    }
}

// ---------------------------------------------------------------------------
extern "C" void kernel_launch(void* const* d_in, const int* in_sizes, int n_in,
                              void* d_out, int out_size, void* d_ws, size_t ws_size,
                              hipStream_t stream)
{
    const float* x      = (const float*)d_in[0];
    const float* conv_w = (const float*)d_in[1];
    const float* w1     = (const float*)d_in[2];
    const float* b1     = (const float*)d_in[3];
    const float* w2     = (const float*)d_in[4];
    const float* b2     = (const float*)d_in[5];
    float* out = (float*)d_out;

    unsigned short* weff_sw = (unsigned short*)d_ws;    // 106496 bf16
    unsigned short* w2f     = weff_sw + NWB;            // 2048 bf16

    const int prep_total = NWB + NW2;                   // 108544
    prep_kernel<<<(prep_total + 255) / 256, 256, 0, stream>>>(conv_w, w1, w2, weff_sw, w2f);
    fused_mlp_kernel<<<BATCH / BM, NTHR, 0, stream>>>(x, b1, b2, weff_sw, w2f, out);
}